// Round 1
// baseline (436.715 us; speedup 1.0000x reference)
//
#include <hip/hip_runtime.h>
#include <math.h>

#define DEVI static __device__ __forceinline__

constexpr int Bn = 4, Cn = 4, Pn = 16384, Sn = 8192, Kn = 16;
constexpr float GN_N = 131072.0f;   // S*K per (b,channel)
constexpr int PART_STRIDE = 96;     // 79 used

// non-contracted f32 ops (pd ordering must not depend on fma fusion)
DEVI float mulrn(float a, float b){ return __fmul_rn(a, b); }
DEVI float addrn(float a, float b){ return __fadd_rn(a, b); }
DEVI float subrn(float a, float b){ return __fsub_rn(a, b); }
DEVI float leaky(float v, float s){ return v >= 0.0f ? v : s * v; }

// ---------------- K1: pack coords + norm into float4 ----------------
__global__ void k_pack(const float* __restrict__ x, float4* __restrict__ pk){
  int i = blockIdx.x * 256 + threadIdx.x;       // 0 .. B*P-1
  int b = i >> 14, p = i & (Pn - 1);
  const float* xb = x + (size_t)b * Cn * Pn;
  float x0 = xb[p], x1 = xb[Pn + p], x2 = xb[2 * Pn + p];
  float n = addrn(addrn(mulrn(x0, x0), mulrn(x1, x1)), mulrn(x2, x2));
  pk[i] = make_float4(x0, x1, x2, n);
}

// ---------------- K2: stable top-16 per (b,s) ----------------
// block = 1024 threads = 16 waves; 16 lanes per s -> 64 s per block.
// Sorted (desc) top-16 lives distributed across the 16 lanes of a group
// (lane r holds rank r). tau = rank-15 value. Insert = shuffle shift (stable).
__launch_bounds__(1024, 2)
__global__ void k_topk(const float4* __restrict__ pk, const int* __restrict__ perm,
                       int* __restrict__ idx){
  __shared__ float4 tile[4096];                 // 64 KiB
  const int b = blockIdx.y;
  const int tid = threadIdx.x;
  const int lane16 = tid & 15;
  const int g = (tid & 63) >> 4;                // group within wave
  const unsigned long long gmask = 0xFFFFull << (g * 16);
  const int s = blockIdx.x * 64 + (tid >> 4);

  const int q = perm[b * Sn + s];
  const float4 sv = pk[b * Pn + q];
  const float sx = sv.x, sy = sv.y, sz = sv.z, sn = sv.w;

  float lv = -INFINITY;  int li = 0;            // my rank's (value, index)
  float tau = -INFINITY;                        // rank-15 value (group-uniform)

  for (int t = 0; t < 4; ++t){
    __syncthreads();
    for (int i = tid; i < 4096; i += 1024)
      tile[i] = pk[b * Pn + t * 4096 + i];
    __syncthreads();

    for (int step = 0; step < 256; ++step){
      const float4 v = tile[step * 16 + lane16];
      const float dot = addrn(addrn(mulrn(v.x, sx), mulrn(v.y, sy)), mulrn(v.z, sz));
      const float pd  = subrn(subrn(mulrn(2.0f, dot), v.w), sn);
      const int   pc  = t * 4096 + step * 16 + lane16;

      unsigned long long m = __ballot(pd > tau) & gmask;
      while (m){
        const int src = __builtin_ctzll(m);     // lowest lane = smallest p (stable)
        const float cv = __shfl(pd, src);
        const int   ci = __shfl(pc, src);
        const float upv = __shfl_up(lv, 1, 16);
        const int   upi = __shfl_up(li, 1, 16);
        const bool keep = (lv >= cv);           // ties: existing (smaller idx) stays above
        const bool ins  = (!keep) && (lane16 == 0 || upv >= cv);
        lv = keep ? lv : (ins ? cv : upv);
        li = keep ? li : (ins ? ci : upi);
        tau = __shfl(lv, 15, 16);
        m &= ~(1ull << src);
        m &= __ballot(pd > tau);
      }
    }
  }
  idx[(b * Sn + s) * Kn + lane16] = li;
}

// scramble: x1[b,c,s',k'] = x[b,c, idx[b, (16s'+k') & 8191, (16s'+k') >> 13]]
DEVI int idxq(const int* __restrict__ idxb, int f){
  return idxb[(f & (Sn - 1)) * Kn + (f >> 13)];
}

DEVI float wred(float v){
  v += __shfl_down(v, 32); v += __shfl_down(v, 16); v += __shfl_down(v, 8);
  v += __shfl_down(v, 4);  v += __shfl_down(v, 2);  v += __shfl_down(v, 1);
  return v;
}

// ---------------- K3: GN moment accumulation ----------------
// Per element: PEmb (10) second moments (55) + means (10); x1 (4) moments (10) + means (4).
// grid (32, B), block 256: one s' per thread (16 elements).
__global__ void k_stats(const float4* __restrict__ pk, const float* __restrict__ x,
                        const int* __restrict__ idx, float* __restrict__ part){
  const int b = blockIdx.y, chunk = blockIdx.x, tid = threadIdx.x;
  const int sp = chunk * 256 + tid;
  const int* idxb = idx + b * Sn * Kn;
  const float* xw = x + ((size_t)b * Cn + 3) * Pn;

  float M10[55], mu10[10], M4[10], mu4[4];
#pragma unroll
  for (int i = 0; i < 55; ++i) M10[i] = 0.f;
#pragma unroll
  for (int i = 0; i < 10; ++i){ mu10[i] = 0.f; M4[i] = 0.f; }
#pragma unroll
  for (int i = 0; i < 4; ++i) mu4[i] = 0.f;

  const int qc = idxq(idxb, sp * 16);
  const float4 cv = pk[b * Pn + qc];

  for (int k = 0; k < 16; ++k){
    const int qn = idxq(idxb, sp * 16 + k);
    const float4 pv = pk[b * Pn + qn];
    const float pw = xw[qn];
    const float dx = subrn(pv.x, cv.x), dy = subrn(pv.y, cv.y), dz = subrn(pv.z, cv.z);
    const float temp = sqrtf(addrn(addrn(mulrn(dx, dx), mulrn(dy, dy)), mulrn(dz, dz)));
    const float E[10] = {pv.x, pv.y, pv.z, cv.x, cv.y, cv.z, dx, dy, dz, temp};
    const float X[4]  = {pv.x, pv.y, pv.z, pw};
    int c = 0;
#pragma unroll
    for (int i = 0; i < 10; ++i){
      mu10[i] += E[i];
#pragma unroll
      for (int j = i; j < 10; ++j){ M10[c] += E[i] * E[j]; ++c; }
    }
    c = 0;
#pragma unroll
    for (int i = 0; i < 4; ++i){
      mu4[i] += X[i];
#pragma unroll
      for (int j = i; j < 4; ++j){ M4[c] += X[i] * X[j]; ++c; }
    }
  }

  __shared__ float red[4][80];
  const int wid = tid >> 6, ln = tid & 63;
#pragma unroll
  for (int i = 0; i < 55; ++i){ float v = wred(M10[i]); if (ln == 0) red[wid][i] = v; }
#pragma unroll
  for (int i = 0; i < 10; ++i){ float v = wred(mu10[i]); if (ln == 0) red[wid][55 + i] = v; }
#pragma unroll
  for (int i = 0; i < 10; ++i){ float v = wred(M4[i]); if (ln == 0) red[wid][65 + i] = v; }
#pragma unroll
  for (int i = 0; i < 4; ++i){ float v = wred(mu4[i]); if (ln == 0) red[wid][75 + i] = v; }
  __syncthreads();
  if (tid < 79){
    float sum = ((red[0][tid] + red[1][tid]) + red[2][tid]) + red[3][tid];
    part[(b * 32 + chunk) * PART_STRIDE + tid] = sum;
  }
}

// ---------------- K4: fold moments into per-(b,ch) scale/shift ----------------
__global__ void k_stats2(const float* __restrict__ part,
                         const float* __restrict__ pos_w, const float* __restrict__ conv_w,
                         const float* __restrict__ bn2_g, const float* __restrict__ bn2_b,
                         const float* __restrict__ bn_g,  const float* __restrict__ bn_b,
                         float2* __restrict__ stats){
  const int t = threadIdx.x;          // 256 = 4b * 64ch
  const int b = t >> 6, o = t & 63;
  float acc[79];
#pragma unroll
  for (int i = 0; i < 79; ++i) acc[i] = 0.f;
  for (int c = 0; c < 32; ++c){
    const float* p = part + (b * 32 + c) * PART_STRIDE;
#pragma unroll
    for (int i = 0; i < 79; ++i) acc[i] += p[i];
  }
  float mean, ex2, gamma, beta;
  if (o < 32){                        // xc channels: conv path, bn_g/bn_b
    const float* w = conv_w + o * 4;
    float m = 0.f, e2 = 0.f; int id = 0;
#pragma unroll
    for (int i = 0; i < 4; ++i){
      m += w[i] * acc[75 + i];
#pragma unroll
      for (int j = i; j < 4; ++j){
        float t2 = w[i] * w[j] * acc[65 + id];
        e2 += (i == j) ? t2 : 2.0f * t2; ++id;
      }
    }
    mean = m / GN_N; ex2 = e2 / GN_N; gamma = bn_g[o]; beta = bn_b[o];
  } else {                            // pe channels: pos path, bn2_g/bn2_b
    const float* w = pos_w + (o - 32) * 10;
    float m = 0.f, e2 = 0.f; int id = 0;
#pragma unroll
    for (int i = 0; i < 10; ++i){
      m += w[i] * acc[55 + i];
#pragma unroll
      for (int j = i; j < 10; ++j){
        float t2 = w[i] * w[j] * acc[id];
        e2 += (i == j) ? t2 : 2.0f * t2; ++id;
      }
    }
    mean = m / GN_N; ex2 = e2 / GN_N; gamma = bn2_g[o - 32]; beta = bn2_b[o - 32];
  }
  const float var = fmaxf(ex2 - mean * mean, 0.f);
  const float rstd = 1.0f / sqrtf(var + 1e-5f);
  const float scale = rstd * gamma;
  stats[b * 64 + o] = make_float2(scale, beta - mean * scale);
}

// ---------------- K5: fused features + attention + output ----------------
// 16 lanes per s' (one (s',k') per lane); block 256 -> 16 s'.
__global__ void k_final(const float4* __restrict__ pk, const float* __restrict__ x,
                        const int* __restrict__ idx, const float2* __restrict__ stats,
                        const float* __restrict__ conv_w, const float* __restrict__ pos_w,
                        const float* __restrict__ att_w1, const float* __restrict__ att_w2,
                        const float* __restrict__ b1_w, const float* __restrict__ b2_w,
                        float* __restrict__ out){
  const int b = blockIdx.y;
  const int tid = threadIdx.x;
  const int k = tid & 15;
  const int sp = blockIdx.x * 16 + (tid >> 4);
  const int* idxb = idx + b * Sn * Kn;
  const float* xw = x + ((size_t)b * Cn + 3) * Pn;

  const int qn = idxq(idxb, sp * 16 + k);
  const float4 pv = pk[b * Pn + qn];
  const float pw = xw[qn];
  const float cx = __shfl(pv.x, 0, 16), cy = __shfl(pv.y, 0, 16);
  const float cz = __shfl(pv.z, 0, 16), cw = __shfl(pw, 0, 16);
  const float dx = subrn(pv.x, cx), dy = subrn(pv.y, cy), dz = subrn(pv.z, cz);
  const float temp = sqrtf(addrn(addrn(mulrn(dx, dx), mulrn(dy, dy)), mulrn(dz, dz)));
  const float E[10]  = {pv.x, pv.y, pv.z, cx, cy, cz, dx, dy, dz, temp};
  const float X4[4]  = {pv.x, pv.y, pv.z, pw};
  const float2* stb = stats + b * 64;

  float feat[64];
  for (int o = 0; o < 32; ++o){       // xc
    float v = 0.f;
#pragma unroll
    for (int c = 0; c < 4; ++c) v = fmaf(conv_w[o * 4 + c], X4[c], v);
    const float2 sc = stb[o];
    feat[o] = leaky(fmaf(v, sc.x, sc.y), 0.2f);
  }
  for (int o = 0; o < 32; ++o){       // pe
    float v = 0.f;
#pragma unroll
    for (int c = 0; c < 10; ++c) v = fmaf(pos_w[o * 10 + c], E[c], v);
    const float2 sc = stb[32 + o];
    feat[32 + o] = leaky(fmaf(v, sc.x, sc.y), 0.2f);
  }

  float logit = 0.f;
  for (int h = 0; h < 32; ++h){
    float v = 0.f;
#pragma unroll
    for (int c = 0; c < 64; ++c) v = fmaf(att_w1[h * 64 + c], feat[c], v);
    logit = fmaf(att_w2[h], leaky(v, 0.2f), logit);
  }
  float mx = logit;
  mx = fmaxf(mx, __shfl_xor(mx, 1, 16)); mx = fmaxf(mx, __shfl_xor(mx, 2, 16));
  mx = fmaxf(mx, __shfl_xor(mx, 4, 16)); mx = fmaxf(mx, __shfl_xor(mx, 8, 16));
  const float e = expf(logit - mx);
  float den = e;
  den += __shfl_xor(den, 1, 16); den += __shfl_xor(den, 2, 16);
  den += __shfl_xor(den, 4, 16); den += __shfl_xor(den, 8, 16);
  const float att = e / den;

#pragma unroll
  for (int c = 0; c < 64; ++c){       // pooled (replicated on all 16 lanes)
    float p = feat[c] * att;
    p += __shfl_xor(p, 1, 16); p += __shfl_xor(p, 2, 16);
    p += __shfl_xor(p, 4, 16); p += __shfl_xor(p, 8, 16);
    feat[c] = p;
  }

  const float X0[4] = {cx, cy, cz, cw};
  float* outb = out + (size_t)b * 68 * Sn;
#pragma unroll
  for (int jj = 0; jj < 4; ++jj){
    const int j = k * 4 + jj;
    float f1 = 0.f;
#pragma unroll
    for (int c = 0; c < 64; ++c) f1 = fmaf(b1_w[j * 64 + c], feat[c], f1);
    float f2 = 0.f;
#pragma unroll
    for (int c = 0; c < 4; ++c) f2 = fmaf(b2_w[j * 4 + c], X0[c], f2);
    outb[(size_t)(4 + j) * Sn + sp] = leaky(f1 + f2, 0.1f);
  }
  if (k == 0){
    outb[0 * Sn + sp] = cx; outb[1 * Sn + sp] = cy;
    outb[2 * Sn + sp] = cz; outb[3 * Sn + sp] = cw;
  }
}

extern "C" void kernel_launch(void* const* d_in, const int* in_sizes, int n_in,
                              void* d_out, int out_size, void* d_ws, size_t ws_size,
                              hipStream_t stream){
  const float* x      = (const float*)d_in[0];
  const int*   perm   = (const int*)d_in[1];
  const float* pos_w  = (const float*)d_in[3];
  const float* bn2_g  = (const float*)d_in[4];
  const float* bn2_b  = (const float*)d_in[5];
  const float* conv_w = (const float*)d_in[6];
  const float* bn_g   = (const float*)d_in[7];
  const float* bn_b   = (const float*)d_in[8];
  const float* att_w1 = (const float*)d_in[9];
  const float* att_w2 = (const float*)d_in[10];
  const float* b1_w   = (const float*)d_in[11];
  const float* b2_w   = (const float*)d_in[12];
  float* out = (float*)d_out;

  char* ws = (char*)d_ws;
  int*    idx   = (int*)ws;                       // 2 MiB
  float4* pk    = (float4*)(ws + 2097152);        // 1 MiB
  float*  part  = (float*)(ws + 3145728);         // 48 KiB
  float2* stats = (float2*)(ws + 3194880);        // 2 KiB

  hipLaunchKernelGGL(k_pack,   dim3(256),      dim3(256),  0, stream, x, pk);
  hipLaunchKernelGGL(k_topk,   dim3(128, 4),   dim3(1024), 0, stream, pk, perm, idx);
  hipLaunchKernelGGL(k_stats,  dim3(32, 4),    dim3(256),  0, stream, pk, x, idx, part);
  hipLaunchKernelGGL(k_stats2, dim3(1),        dim3(256),  0, stream, part, pos_w, conv_w,
                     bn2_g, bn2_b, bn_g, bn_b, stats);
  hipLaunchKernelGGL(k_final,  dim3(512, 4),   dim3(256),  0, stream, pk, x, idx, stats,
                     conv_w, pos_w, att_w1, att_w2, b1_w, b2_w, out);
}